// Round 9
// baseline (272.011 us; speedup 1.0000x reference)
//
#include <hip/hip_runtime.h>
#include <hip/hip_bf16.h>
#include <stdint.h>

#define B_ 2
#define S_ 2048
#define D_ 1024
#define H_ 16
#define DK_ 64
#define M_ 4096   // B_*S_
#define K_ 1024

typedef unsigned short u16;
typedef u16   u16x4  __attribute__((ext_vector_type(4)));
typedef short short8 __attribute__((ext_vector_type(8)));
typedef float f32x4  __attribute__((ext_vector_type(4)));
typedef uint32_t u32x4 __attribute__((ext_vector_type(4)));

__device__ __forceinline__ u16 f2bf(float f) {
  uint32_t u = __builtin_bit_cast(uint32_t, f);
  u += 0x7FFFu + ((u >> 16) & 1u);   // RNE
  return (u16)(u >> 16);
}

__device__ __forceinline__ uint32_t cvtpk(float lo, float hi) {
  uint32_t r;
  asm("v_cvt_pk_bf16_f32 %0, %1, %2" : "=v"(r) : "v"(lo), "v"(hi));
  return r;
}

__device__ __forceinline__ void gload_lds16(const void* g, void* l) {
  __builtin_amdgcn_global_load_lds(
      (const __attribute__((address_space(1))) void*)g,
      (__attribute__((address_space(3))) void*)l, 16, 0, 0);
}

// ---------------- fp32 -> bf16 weight converts, 4 tensors in one launch ----
__global__ __launch_bounds__(256) void cvt4w(const float* __restrict__ a,
                                             const float* __restrict__ b,
                                             const float* __restrict__ c,
                                             const float* __restrict__ d,
                                             u16* __restrict__ oa, u16* __restrict__ ob,
                                             u16* __restrict__ oc, u16* __restrict__ od) {
  const int z = blockIdx.y;
  const float* in = z == 0 ? a : (z == 1 ? b : (z == 2 ? c : d));
  u16* out = z == 0 ? oa : (z == 1 ? ob : (z == 2 ? oc : od));
  const int i = (blockIdx.x * 256 + threadIdx.x) * 4;
  const float4 v = *(const float4*)(in + i);
  u16x4 o;
  o[0] = f2bf(v.x); o[1] = f2bf(v.y); o[2] = f2bf(v.z); o[3] = f2bf(v.w);
  *(u16x4*)(out + i) = o;
}

// ---------------- fused QKV GEMM: dbuf BK=32, STAGE-early ------------------
// flash64-proven 2-phase: STAGE(t+1,buf^1) issued BEFORE compute(t), single
// barrier per step AFTER compute => load latency hidden under MFMA (round-8
// counters: HBM 10%, MfmaUtil 12%, Occ 14% = latency-bound stage drain).
// 48 KB LDS => 3 blocks/CU.  XCD-chunked tile map (round-8: FETCH 200->42MB).
// z=0: Q -> [B,H,S,DK] *0.125   z=1: K -> [B,H,S,DK]   z=2: V -> [B,H,DK,S]
__global__ __launch_bounds__(256) void gemm_qkv(
    const float* __restrict__ Aq, const float* __restrict__ Ak, const float* __restrict__ Av,
    const u16* __restrict__ Wqp, const u16* __restrict__ Wkp, const u16* __restrict__ Wvp,
    const float* __restrict__ bqp, const float* __restrict__ bkp, const float* __restrict__ bvp,
    u16* __restrict__ oq, u16* __restrict__ okk, u16* __restrict__ ov) {
  __shared__ float As[2][128 * 32];   // 16 KB x2, 128 B rows
  __shared__ u16  Bs[2][128 * 32];    //  8 KB x2,  64 B rows

  const int g = blockIdx.x;
  const int T = (g & 7) * 96 + (g >> 3);   // bijective XCD chunk (768 = 8*96)
  const int z = T >> 8;
  const int rem = T & 255;
  const int m0 = (rem >> 3) * 128, n0 = (rem & 7) * 128;

  const float* A    = z == 0 ? Aq  : (z == 1 ? Ak  : Av);
  const u16*   W    = z == 0 ? Wqp : (z == 1 ? Wkp : Wvp);
  const float* bias = z == 0 ? bqp : (z == 1 ? bkp : bvp);
  u16* out          = z == 0 ? oq  : (z == 1 ? okk : ov);
  const float scale = z == 0 ? 0.125f : 1.0f;

  const int tid = threadIdx.x;
  const int w = tid >> 6, lane = tid & 63;
  const int lr = lane & 15, lk = lane >> 4;
  const int wr = w >> 1, wc = w & 1;

  f32x4 acc[4][4] = {};

  const int arow   = tid >> 3;                                // 0..31
  const int acolsz = ((tid & 7) * 16) ^ ((arow & 7) << 4);    // A: 8 slots/row
  const int brow   = tid >> 2;                                // 0..63
  const int bcolsz = ((tid & 3) * 16) ^ ((brow & 3) << 4);    // B: 4 slots/row
  const int raswz  = (lr & 7) << 4;
  const int rbswz  = (lr & 3) << 4;
  const float* Ab = A + (size_t)(m0 + arow) * K_;
  const u16*   Wb = W + (size_t)(n0 + brow) * K_;

  auto STAGE = [&](int k0, int d) {
#pragma unroll
    for (int i = 0; i < 4; ++i)
      gload_lds16((const char*)(Ab + (size_t)(i * 32) * K_ + k0) + acolsz,
                  (char*)As[d] + i * 4096 + w * 1024);
#pragma unroll
    for (int i = 0; i < 2; ++i)
      gload_lds16((const char*)(Wb + (size_t)(i * 64) * K_ + k0) + bcolsz,
                  (char*)Bs[d] + i * 4096 + w * 1024);
  };

  STAGE(0, 0);
  __syncthreads();

  int cur = 0;
  for (int t = 0; t < 32; ++t) {
    if (t + 1 < 32) STAGE((t + 1) * 32, cur ^ 1);   // prefetch flies under MFMA

    short8 af[4], bf[4];
#pragma unroll
    for (int mi = 0; mi < 4; ++mi) {
      const char* ap = (const char*)As[cur] + (wr * 64 + mi * 16 + lr) * 128;
      const f32x4 lo = *(const f32x4*)(ap + ((lk * 32) ^ raswz));
      const f32x4 hi = *(const f32x4*)(ap + ((lk * 32 + 16) ^ raswz));
      u32x4 pk;
      pk[0] = cvtpk(lo[0], lo[1]);
      pk[1] = cvtpk(lo[2], lo[3]);
      pk[2] = cvtpk(hi[0], hi[1]);
      pk[3] = cvtpk(hi[2], hi[3]);
      af[mi] = __builtin_bit_cast(short8, pk);
    }
#pragma unroll
    for (int nj = 0; nj < 4; ++nj)
      bf[nj] = *(const short8*)((const char*)Bs[cur] + (wc * 64 + nj * 16 + lr) * 64 +
                                ((lk * 16) ^ rbswz));
#pragma unroll
    for (int mi = 0; mi < 4; ++mi)
#pragma unroll
      for (int nj = 0; nj < 4; ++nj)
        acc[mi][nj] = __builtin_amdgcn_mfma_f32_16x16x32_bf16(af[mi], bf[nj],
                                                              acc[mi][nj], 0, 0, 0);
    __syncthreads();   // drains prefetch (had full compute phase to land)
    cur ^= 1;
  }

#pragma unroll
  for (int nj = 0; nj < 4; ++nj) {
    const int col = n0 + wc * 64 + nj * 16 + lr;
    const float bv = bias[col];
    const int h = col >> 6, dk = col & 63;
#pragma unroll
    for (int mi = 0; mi < 4; ++mi) {
#pragma unroll
      for (int r = 0; r < 4; ++r) {
        const int row = m0 + wr * 64 + mi * 16 + lk * 4 + r;
        const float val = (acc[mi][nj][r] + bv) * scale;
        const int b = row >> 11, s = row & 2047;
        if (z != 2)
          out[((size_t)(b * H_ + h) * S_ + s) * DK_ + dk] = f2bf(val);
        else
          out[((size_t)(b * H_ + h) * DK_ + dk) * S_ + s] = f2bf(val);
      }
    }
  }
}

// ---------------- out-projection GEMM: dbuf BK=32, bf16 A ------------------
__global__ __launch_bounds__(256) void gemm_out(const u16* __restrict__ A,
                                                const u16* __restrict__ W,
                                                const float* __restrict__ bias,
                                                float* __restrict__ out) {
  __shared__ u16 As[2][128 * 32];   // 8 KB x2, 64 B rows
  __shared__ u16 Bs[2][128 * 32];
  const int g = blockIdx.x;
  const int T = (g & 7) * 32 + (g >> 3);   // bijective XCD chunk (256 = 8*32)
  const int m0 = (T >> 3) * 128, n0 = (T & 7) * 128;

  const int tid = threadIdx.x;
  const int w = tid >> 6, lane = tid & 63;
  const int lr = lane & 15, lk = lane >> 4;
  const int wr = w >> 1, wc = w & 1;

  f32x4 acc[4][4] = {};

  const int brow   = tid >> 2;                                // 0..63
  const int bcolsz = ((tid & 3) * 16) ^ ((brow & 3) << 4);
  const int rbswz  = (lr & 3) << 4;
  const u16* Abase = A + (size_t)(m0 + brow) * K_;
  const u16* Wbase = W + (size_t)(n0 + brow) * K_;

  auto STAGE = [&](int k0, int d) {
#pragma unroll
    for (int i = 0; i < 2; ++i) {
      gload_lds16((const char*)(Abase + (size_t)(i * 64) * K_ + k0) + bcolsz,
                  (char*)As[d] + i * 4096 + w * 1024);
      gload_lds16((const char*)(Wbase + (size_t)(i * 64) * K_ + k0) + bcolsz,
                  (char*)Bs[d] + i * 4096 + w * 1024);
    }
  };

  STAGE(0, 0);
  __syncthreads();

  int cur = 0;
  for (int t = 0; t < 32; ++t) {
    if (t + 1 < 32) STAGE((t + 1) * 32, cur ^ 1);

    short8 af[4], bf[4];
#pragma unroll
    for (int mi = 0; mi < 4; ++mi)
      af[mi] = *(const short8*)((const char*)As[cur] + (wr * 64 + mi * 16 + lr) * 64 +
                                ((lk * 16) ^ rbswz));
#pragma unroll
    for (int nj = 0; nj < 4; ++nj)
      bf[nj] = *(const short8*)((const char*)Bs[cur] + (wc * 64 + nj * 16 + lr) * 64 +
                                ((lk * 16) ^ rbswz));
#pragma unroll
    for (int mi = 0; mi < 4; ++mi)
#pragma unroll
      for (int nj = 0; nj < 4; ++nj)
        acc[mi][nj] = __builtin_amdgcn_mfma_f32_16x16x32_bf16(af[mi], bf[nj],
                                                              acc[mi][nj], 0, 0, 0);
    __syncthreads();
    cur ^= 1;
  }

#pragma unroll
  for (int nj = 0; nj < 4; ++nj) {
    const int col = n0 + wc * 64 + nj * 16 + lr;
    const float bv = bias[col];
#pragma unroll
    for (int mi = 0; mi < 4; ++mi)
#pragma unroll
      for (int r = 0; r < 4; ++r) {
        const int row = m0 + wr * 64 + mi * 16 + lk * 4 + r;
        out[(size_t)row * D_ + col] = acc[mi][nj][r] + bv;
      }
  }
}

// ---------------- flash attention v2: double-buffered, XCD-local -----------
__global__ __launch_bounds__(256) void flash64(const u16* __restrict__ Qh,
                                               const u16* __restrict__ Kh,
                                               const u16* __restrict__ Vt,
                                               u16* __restrict__ O,
                                               float* __restrict__ AW) {
  __shared__ u16 Ks[2][64 * 64];
  __shared__ u16 Vs[2][64 * 64];   // [dk][kv]
  __shared__ u16 Ps[64 * 64];
  const int tid = threadIdx.x;
  const int w = tid >> 6, lane = tid & 63;
  const int lr = lane & 15, lk = lane >> 4;
  const int bh = blockIdx.x;                    // b*H + h
  const int qt = (gridDim.y - 1) - blockIdx.y;  // longest-first
  const int q0 = qt * 64;
  const int b = bh >> 4, h = bh & 15;
  const int nt = qt + 1;

  const u16* Qg = Qh + ((size_t)bh * S_ + q0 + w * 16 + lr) * DK_;
  short8 qf[2];
  qf[0] = *(const short8*)(Qg + lk * 8);
  qf[1] = *(const short8*)(Qg + 32 + lk * 8);

  float mrow[4], lrow[4];
  f32x4 o[4] = {};
#pragma unroll
  for (int r = 0; r < 4; ++r) { mrow[r] = -__builtin_inff(); lrow[r] = 0.f; }

  const int trow = tid >> 3;
  const int tswz = ((tid & 7) * 16) ^ ((trow & 7) << 4);   // pre-swizzled source col
  const int rswz = (lr & 7) << 4;                          // read-side XOR
  const u16* Kgb = Kh + (size_t)bh * S_ * DK_;
  const u16* Vgb = Vt + (size_t)bh * DK_ * S_;

  auto STAGE = [&](int t, int d) {
    const int kv0 = t * 64;
#pragma unroll
    for (int i = 0; i < 2; ++i) {
      const char* gk = (const char*)(Kgb + (size_t)(kv0 + i * 32 + trow) * DK_) + tswz;
      gload_lds16(gk, (char*)Ks[d] + i * 4096 + w * 1024);
      const char* gv = (const char*)(Vgb + (size_t)(i * 32 + trow) * S_ + kv0) + tswz;
      gload_lds16(gv, (char*)Vs[d] + i * 4096 + w * 1024);
    }
  };

  STAGE(0, 0);
  __syncthreads();

  int cur = 0;
  for (int t = 0; t < nt; ++t) {
    if (t + 1 < nt) STAGE(t + 1, cur ^ 1);   // issue next-tile loads early

    // S = Q K^T (Q already has 1/sqrt(dk))
    f32x4 sa[4] = {};
#pragma unroll
    for (int kk = 0; kk < 2; ++kk)
#pragma unroll
      for (int nj = 0; nj < 4; ++nj) {
        const short8 kf = *(const short8*)((const char*)Ks[cur] + (nj * 16 + lr) * 128 +
                                           ((kk * 64 + lk * 16) ^ rswz));
        sa[nj] = __builtin_amdgcn_mfma_f32_16x16x32_bf16(qf[kk], kf, sa[nj], 0, 0, 0);
      }

    if (t == qt) {  // diagonal tile: causal mask (col > row -> -inf)
#pragma unroll
      for (int nj = 0; nj < 4; ++nj)
#pragma unroll
        for (int r = 0; r < 4; ++r)
          if (nj * 16 + lr > w * 16 + lk * 4 + r) sa[nj][r] = -1e30f;
    }

    // online softmax: max reduced across 16 lanes; l kept as PER-LANE partial
#pragma unroll
    for (int r = 0; r < 4; ++r) {
      float mx = fmaxf(fmaxf(sa[0][r], sa[1][r]), fmaxf(sa[2][r], sa[3][r]));
#pragma unroll
      for (int d = 1; d < 16; d <<= 1) mx = fmaxf(mx, __shfl_xor(mx, d));
      const float mn = fmaxf(mrow[r], mx);
      const float sc = __expf(mrow[r] - mn);   // lane-uniform within row
      mrow[r] = mn;
      float rs = 0.f;
#pragma unroll
      for (int nj = 0; nj < 4; ++nj) {
        const float p = __expf(sa[nj][r] - mn);
        sa[nj][r] = p;
        rs += p;
      }
      lrow[r] = lrow[r] * sc + rs;             // per-lane partial (4 cols/lane)
#pragma unroll
      for (int nj = 0; nj < 4; ++nj) o[nj][r] *= sc;
    }

    // P -> LDS (bf16, swizzled; wave-private 16-row slab, no barrier needed)
#pragma unroll
    for (int nj = 0; nj < 4; ++nj)
#pragma unroll
      for (int r = 0; r < 4; ++r) {
        const int rp = w * 16 + lk * 4 + r;
        *(u16*)((char*)Ps + rp * 128 + (((nj * 16 + lr) * 2) ^ ((rp & 7) << 4))) =
            f2bf(sa[nj][r]);
      }

    // O += P @ V
#pragma unroll
    for (int kk = 0; kk < 2; ++kk) {
      const short8 pa = *(const short8*)((const char*)Ps + (w * 16 + lr) * 128 +
                                         ((kk * 64 + lk * 16) ^ rswz));
#pragma unroll
      for (int nj = 0; nj < 4; ++nj) {
        const short8 vf = *(const short8*)((const char*)Vs[cur] + (nj * 16 + lr) * 128 +
                                           ((kk * 64 + lk * 16) ^ rswz));
        o[nj] = __builtin_amdgcn_mfma_f32_16x16x32_bf16(pa, vf, o[nj], 0, 0, 0);
      }
    }
    __syncthreads();   // drains next-tile stage (flew during compute) + barrier
    cur ^= 1;
  }

#pragma unroll
  for (int r = 0; r < 4; ++r) {
    // finalize l: reduce per-lane partials across the row's 16 lanes
    float lt = lrow[r];
#pragma unroll
    for (int d = 1; d < 16; d <<= 1) lt += __shfl_xor(lt, d);
    const int rowq = q0 + w * 16 + lk * 4 + r;
    const float inv = 1.f / lt;
    float rsum = 0.f;
#pragma unroll
    for (int nj = 0; nj < 4; ++nj) {
      const float v = o[nj][r] * inv;
      O[((size_t)(b * S_ + rowq)) * D_ + h * 64 + nj * 16 + lr] = f2bf(v);
      rsum += v;
    }
#pragma unroll
    for (int d = 1; d < 16; d <<= 1) rsum += __shfl_xor(rsum, d);
    if (lr == 0) AW[(size_t)bh * S_ + rowq] = rsum * (1.f / 64.f);
  }
}

extern "C" void kernel_launch(void* const* d_in, const int* in_sizes, int n_in,
                              void* d_out, int out_size, void* d_ws, size_t ws_size,
                              hipStream_t stream) {
  const float* q  = (const float*)d_in[0];
  const float* k  = (const float*)d_in[1];
  const float* v  = (const float*)d_in[2];
  const float* Wq = (const float*)d_in[4];
  const float* bq = (const float*)d_in[5];
  const float* Wk = (const float*)d_in[6];
  const float* bk = (const float*)d_in[7];
  const float* Wv = (const float*)d_in[8];
  const float* bv = (const float*)d_in[9];
  const float* Wo = (const float*)d_in[10];
  const float* bo = (const float*)d_in[11];
  float* out = (float*)d_out;
  float* aw  = out + (size_t)M_ * D_;   // attn_weights tail [B,H,S]

  char* ws = (char*)d_ws;               // 40 MB total
  u16* Qh  = (u16*)(ws);                //  0- 8 MB
  u16* Kh  = (u16*)(ws + (8u << 20));   //  8-16
  u16* Vtb = (u16*)(ws + (16u << 20));  // 16-24
  u16* Ob  = (u16*)(ws + (24u << 20));  // 24-32
  u16* Wqb = (u16*)(ws + (32u << 20));  // 32-34
  u16* Wkb = (u16*)(ws + (34u << 20));
  u16* Wvb = (u16*)(ws + (36u << 20));
  u16* Wob = (u16*)(ws + (38u << 20));

  cvt4w<<<dim3(1024, 4), 256, 0, stream>>>(Wq, Wk, Wv, Wo, Wqb, Wkb, Wvb, Wob);

  gemm_qkv<<<768, 256, 0, stream>>>(q, k, v, Wqb, Wkb, Wvb,
                                    bq, bk, bv, Qh, Kh, Vtb);

  flash64<<<dim3(B_ * H_, S_ / 64), 256, 0, stream>>>(Qh, Kh, Vtb, Ob, aw);

  gemm_out<<<256, 256, 0, stream>>>(Ob, Wob, bo, out);
}